// Round 4
// baseline (5197.822 us; speedup 1.0000x reference)
//
#include <hip/hip_runtime.h>
#include <math.h>

#define N_IN   65536
#define N_UP   262144
#define N_OUT  131072
#define C_IN   128
#define C_OUT  64
#define K1     27
#define K2     27
#define K3     16
#define EPSV   1e-6f
#define TSHIFT 8            // 256-row output tiles (64KB LDS, 2 blocks/CU)

// ---------------------------------------------------------------------------
// Pass A: histogram pairs into (dst-block, k) bins.
template <int KNUM, int MSHIFT>
__global__ __launch_bounds__(256) void hist_kernel(
    const int* __restrict__ kout, int* __restrict__ hist)
{
    const int n = KNUM << MSHIFT;
    for (int j = blockIdx.x * 256 + threadIdx.x; j < n; j += gridDim.x * 256) {
        const int k = j >> MSHIFT;
        const int b = kout[j] >> TSHIFT;
        atomicAdd(hist + b * KNUM + k, 1);
    }
}

// Pass B: single-block exclusive scan over nbins bins -> offs[nbins+1], cursor.
__global__ __launch_bounds__(1024) void scan_kernel(
    const int* __restrict__ hist, int* __restrict__ offs,
    int* __restrict__ cursor, int nbins)
{
    __shared__ int ps[1024];
    const int t = threadIdx.x;
    const int per = (nbins + 1023) >> 10;
    const int base = t * per;
    int s = 0;
    for (int i = 0; i < per; ++i) {
        const int b = base + i;
        if (b < nbins) s += hist[b];
    }
    ps[t] = s;
    __syncthreads();
    for (int off = 1; off < 1024; off <<= 1) {
        const int v = (t >= off) ? ps[t - off] : 0;
        __syncthreads();
        ps[t] += v;
        __syncthreads();
    }
    int run = (t == 0) ? 0 : ps[t - 1];
    for (int i = 0; i < per; ++i) {
        const int b = base + i;
        if (b < nbins) {
            const int h = hist[b];
            offs[b] = run;
            cursor[b] = run;
            run += h;
        }
    }
    if (t == 1023) offs[nbins] = run;   // total (t=1023's own bins, if any, added above)
}

// Pass C: scatter pairs to sorted positions. word = (dst & 255)<<18 | src.
template <int KNUM, int MSHIFT>
__global__ __launch_bounds__(256) void scatter_kernel(
    const int* __restrict__ kin, const int* __restrict__ kout,
    int* __restrict__ cursor, unsigned* __restrict__ sorted)
{
    const int n = KNUM << MSHIFT;
    for (int j = blockIdx.x * 256 + threadIdx.x; j < n; j += gridDim.x * 256) {
        const int k   = j >> MSHIFT;
        const int dst = kout[j];
        const int b   = dst >> TSHIFT;
        const int pos = atomicAdd(cursor + b * KNUM + k, 1);
        sorted[pos] = (unsigned)kin[j] |
                      ((unsigned)(dst & ((1 << TSHIFT) - 1)) << 18);
    }
}

// ---------------------------------------------------------------------------
// Output-stationary conv: workgroup owns a 256-row tile in LDS. Wave w walks
// k = w, w+4, ... (k wave-uniform -> W via s_load broadcast). Per 64-pair
// batch: per-lane float4 gathers with 2-chunk rotation, 64x(CIN) outer-product
// FMA into acc[64], then LDS atomics into the tile (channel rotated by row to
// spread banks: bank = (c+rl)&31). Epilogue: plain coalesced stores covering
// every row -> no global memset, zero global float atomics.
template <int CIN, int KNUM>
__global__ __launch_bounds__(256) void conv_tile(
    const float* __restrict__ X, const float* __restrict__ W,
    const unsigned* __restrict__ sorted, const int* __restrict__ offs,
    float* __restrict__ outp)
{
    __shared__ float tile[256][64];      // [r][(c + r) & 63]
    const int lane   = threadIdx.x & 63;
    const int wv     = threadIdx.x >> 6;
    const int bucket = blockIdx.x;
    constexpr int KC = CIN / 16;

    // zero tile
    float4* tf = (float4*)&tile[0][0];
#pragma unroll
    for (int i = 0; i < 16; ++i)
        tf[threadIdx.x + 256 * i] = float4{0.f, 0.f, 0.f, 0.f};
    __syncthreads();

    for (int k = wv; k < KNUM; k += 4) {
        const int s = offs[bucket * KNUM + k];
        const int e = offs[bucket * KNUM + k + 1];
        const float* Wk = W +
            (size_t)__builtin_amdgcn_readfirstlane(k) * (CIN * 64);

        for (int bs = s; bs < e; bs += 64) {
            const int idx    = bs + lane;
            const bool valid = idx < e;
            const unsigned word = valid ? sorted[idx] : 0u;
            const int src = word & 0x3FFFF;
            const int rl  = word >> 18;

            const float4* xr = (const float4*)(X + (size_t)src * CIN);

            float acc[64];
#pragma unroll
            for (int c = 0; c < 64; ++c) acc[c] = 0.f;

            float4 xa0 = xr[0], xa1 = xr[1], xa2 = xr[2], xa3 = xr[3];
            float4 xb0 = xr[4], xb1 = xr[5], xb2 = xr[6], xb3 = xr[7];

            for (int kc = 0; kc < KC; ++kc) {   // rolled: compiler decides
                float4 xc0, xc1, xc2, xc3;
                if (kc + 2 < KC) {
                    xc0 = xr[(kc + 2) * 4 + 0];
                    xc1 = xr[(kc + 2) * 4 + 1];
                    xc2 = xr[(kc + 2) * 4 + 2];
                    xc3 = xr[(kc + 2) * 4 + 3];
                } else {
                    xc0 = xa0; xc1 = xa1; xc2 = xa2; xc3 = xa3;
                }

                float xs[16];
                xs[0]=xa0.x; xs[1]=xa0.y; xs[2]=xa0.z; xs[3]=xa0.w;
                xs[4]=xa1.x; xs[5]=xa1.y; xs[6]=xa1.z; xs[7]=xa1.w;
                xs[8]=xa2.x; xs[9]=xa2.y; xs[10]=xa2.z; xs[11]=xa2.w;
                xs[12]=xa3.x; xs[13]=xa3.y; xs[14]=xa3.z; xs[15]=xa3.w;

                const float* wrow = Wk + kc * 16 * 64;
#pragma unroll
                for (int i = 0; i < 16; ++i) {
                    const float xi = xs[i];
                    const float* wr = wrow + i * 64;   // wave-uniform -> s_load
#pragma unroll
                    for (int c = 0; c < 64; ++c)
                        acc[c] = fmaf(xi, wr[c], acc[c]);
                }
                xa0 = xb0; xa1 = xb1; xa2 = xb2; xa3 = xb3;
                xb0 = xc0; xb1 = xc1; xb2 = xc2; xb3 = xc3;
            }

            if (valid) {
#pragma unroll
                for (int c = 0; c < 64; ++c)
                    atomicAdd(&tile[rl][(c + rl) & 63], acc[c]);
            }
        }
    }
    __syncthreads();

    // epilogue: each wave stores 64 rows, coalesced 256B per instruction
    const int rbase = wv * 64;
    for (int r = rbase; r < rbase + 64; ++r) {
        const float v = tile[r][(lane + r) & 63];
        outp[((size_t)(bucket << TSHIFT) + r) * 64 + lane] = v;
    }
}

// ---------------------------------------------------------------------------
// Per-channel sum/sumsq; LDS reduce across the block's 4 waves, then atomics.
__global__ __launch_bounds__(256) void stats_kernel(
    const float* __restrict__ x, int nrows, float* __restrict__ stats)
{
    __shared__ float sh[2][4][64];
    const int c  = threadIdx.x & 63;
    const int rw = threadIdx.x >> 6;
    float s = 0.f, s2 = 0.f;
    for (int r = blockIdx.x * 4 + rw; r < nrows; r += gridDim.x * 4) {
        float v = x[(size_t)r * 64 + c];
        s += v;
        s2 = fmaf(v, v, s2);
    }
    sh[0][rw][c] = s;
    sh[1][rw][c] = s2;
    __syncthreads();
    if (rw == 0) {
        s  = (sh[0][0][c] + sh[0][1][c]) + (sh[0][2][c] + sh[0][3][c]);
        s2 = (sh[1][0][c] + sh[1][1][c]) + (sh[1][2][c] + sh[1][3][c]);
        atomicAdd(stats + c, s);
        atomicAdd(stats + 64 + c, s2);
    }
}

// stats[128+c]=mean, stats[192+c]=rsqrt(var+eps)
__global__ void finalize_stats(float* stats, float inv_n)
{
    const int c = threadIdx.x;   // 64 threads
    float mu  = stats[c] * inv_n;
    float var = stats[64 + c] * inv_n - mu * mu;
    stats[128 + c] = mu;
    stats[192 + c] = rsqrtf(var + EPSV);
}

// x = elu((x-mu)*scale) (+ fp32 encoder skip if enc != null), in place.
__global__ __launch_bounds__(256) void norm_elu(
    float* __restrict__ x, const float* __restrict__ stats,
    const float* __restrict__ enc)
{
    const int i = blockIdx.x * 256 + threadIdx.x;
    const int c = i & 63;
    float v = (x[i] - stats[128 + c]) * stats[192 + c];
    v = (v > 0.f) ? v : expm1f(v);
    if (enc) v += enc[i];
    x[i] = v;
}

// Final: normalize+elu, pruning dot, keep mask, fp32 outputs.
__global__ __launch_bounds__(256) void final_kernel(
    const float* __restrict__ x, const float* __restrict__ stats,
    const float* __restrict__ Wp, const float* __restrict__ bp,
    float* __restrict__ outp)
{
    const int lane = threadIdx.x & 63;
    const int wid  = threadIdx.x >> 6;
    const int row  = blockIdx.x * 4 + wid;

    float v = (x[(size_t)row * 64 + lane] - stats[128 + lane]) * stats[192 + lane];
    v = (v > 0.f) ? v : expm1f(v);

    float p = v * Wp[lane];
#pragma unroll
    for (int m = 1; m < 64; m <<= 1)
        p += __shfl_xor(p, m, 64);
    p += bp[0];

    const bool keep = p > 0.0f;
    outp[(size_t)row * 64 + lane] = keep ? v : 0.f;
    if (lane == 0)
        outp[(size_t)N_OUT * 64 + row] = keep ? 1.f : 0.f;
}

extern "C" void kernel_launch(void* const* d_in, const int* in_sizes, int n_in,
                              void* d_out, int out_size, void* d_ws, size_t ws_size,
                              hipStream_t stream)
{
    const float* in_feats = (const float*)d_in[0];   // [65536,128] f32
    const float* enc      = (const float*)d_in[1];   // [262144,64] f32
    const float* W1       = (const float*)d_in[2];   // [27,128,64] f32
    const float* W2       = (const float*)d_in[3];   // [27,64,64]  f32
    const float* W3       = (const float*)d_in[4];   // [16,64,64]  f32
    const float* Wp       = (const float*)d_in[5];   // [64,1] f32
    const float* bp       = (const float*)d_in[6];   // [1] f32
    const int* kin1  = (const int*)d_in[7];
    const int* kout1 = (const int*)d_in[8];
    const int* kin2  = (const int*)d_in[9];
    const int* kout2 = (const int*)d_in[10];
    const int* kin3  = (const int*)d_in[11];
    const int* kout3 = (const int*)d_in[12];
    float* outp = (float*)d_out;

    // Workspace: stays within the proven 128MB+stats footprint.
    char* ws = (char*)d_ws;
    float* up_a   = (float*)ws;                      // 64 MB [262144,64]
    float* up_b   = (float*)(ws + 67108864);         // 64 MB [262144,64]
    float* out3   = up_a;                            // 32 MB reuse after conv2
    float* statsA = (float*)(ws + 134217728);        // 256 f32 each
    float* statsB = statsA + 256;
    float* statsC = statsA + 512;

    // Sort scratch lives in d_out (>= 34MB, dead until final_kernel, and
    // fully overwritten by it): sorted (<=13.5MiB) + hist/offs/cursor.
    char* scratch = (char*)d_out;
    unsigned* sorted = (unsigned*)scratch;               // [0, 16MB)
    int* hist   = (int*)(scratch + 16777216);            // 128 KB slot
    int* offs   = (int*)(scratch + 16908288);            // 128 KB slot
    int* cursor = (int*)(scratch + 17039360);            // 128 KB slot
                                                         // end: 16.4 MB < 33.5 MB

    const int NBK1 = N_UP  >> TSHIFT;   // 1024 buckets
    const int NBK3 = N_OUT >> TSHIFT;   // 512 buckets
    const int NB1  = NBK1 * K1;         // 27648 bins (conv1, conv2)
    const int NB3  = NBK3 * K3;         // 8192 bins (conv3)

    (void)hipMemsetAsync(statsA, 0, 3 * 256 * 4, stream);

    // ---- dec_block_1a: conv-transpose (input_feats -> up_a), CIN=128
    (void)hipMemsetAsync(hist, 0, NB1 * 4, stream);
    hist_kernel<K1, 16><<<1024, 256, 0, stream>>>(kout1, hist);
    scan_kernel<<<1, 1024, 0, stream>>>(hist, offs, cursor, NB1);
    scatter_kernel<K1, 16><<<1024, 256, 0, stream>>>(kin1, kout1, cursor, sorted);
    conv_tile<128, K1><<<NBK1, 256, 0, stream>>>(in_feats, W1, sorted, offs, up_a);
    stats_kernel<<<512, 256, 0, stream>>>(up_a, N_UP, statsA);
    finalize_stats<<<1, 64, 0, stream>>>(statsA, 1.f / N_UP);
    norm_elu<<<(N_UP * 64) / 256, 256, 0, stream>>>(up_a, statsA, nullptr);

    // ---- dec_block_1b: conv 3x3x3 (up_a -> up_b), CIN=64
    (void)hipMemsetAsync(hist, 0, NB1 * 4, stream);
    hist_kernel<K2, 17><<<1024, 256, 0, stream>>>(kout2, hist);
    scan_kernel<<<1, 1024, 0, stream>>>(hist, offs, cursor, NB1);
    scatter_kernel<K2, 17><<<1024, 256, 0, stream>>>(kin2, kout2, cursor, sorted);
    conv_tile<64, K2><<<NBK1, 256, 0, stream>>>(up_a, W2, sorted, offs, up_b);
    stats_kernel<<<512, 256, 0, stream>>>(up_b, N_UP, statsB);
    finalize_stats<<<1, 64, 0, stream>>>(statsB, 1.f / N_UP);
    norm_elu<<<(N_UP * 64) / 256, 256, 0, stream>>>(up_b, statsB, enc);  // + skip

    // ---- dec_block_2: conv k=2 (up_b -> out3), CIN=64
    (void)hipMemsetAsync(hist, 0, NB3 * 4, stream);
    hist_kernel<K3, 17><<<1024, 256, 0, stream>>>(kout3, hist);
    scan_kernel<<<1, 1024, 0, stream>>>(hist, offs, cursor, NB3);
    scatter_kernel<K3, 17><<<1024, 256, 0, stream>>>(kin3, kout3, cursor, sorted);
    conv_tile<64, K3><<<NBK3, 256, 0, stream>>>(up_b, W3, sorted, offs, out3);
    stats_kernel<<<512, 256, 0, stream>>>(out3, N_OUT, statsC);
    finalize_stats<<<1, 64, 0, stream>>>(statsC, 1.f / N_OUT);

    // ---- pruning head + fp32 outputs (overwrites all scratch in d_out)
    final_kernel<<<N_OUT / 4, 256, 0, stream>>>(out3, statsC, Wp, bp, outp);
}